// Round 7
// baseline (210.903 us; speedup 1.0000x reference)
//
#include <hip/hip_runtime.h>
#include <cstdint>
#include <cstddef>

#define DMAX 8732
#define JT 0.5f
#define CC 81

__device__ __forceinline__ float sl1(float d) {
    float ad = fabsf(d);
    return (ad < 1.0f) ? 0.5f * d * d : ad - 0.5f;
}

// ---------------- Kernel A: per-batch matching ----------------
template<int TT>
__global__ __launch_bounds__(256) void match_kernel(
    const float* __restrict__ loc, const float* __restrict__ dbox,
    const float* __restrict__ targets, int D,
    int* __restrict__ conf_t, int* __restrict__ num_pos,
    float* __restrict__ loss_l_part, float* __restrict__ posce)
{
    const int b = blockIdx.x;
    const int tid = threadIdx.x;

    __shared__ float s_tr[TT][4];
    __shared__ float s_area[TT];
    __shared__ int   s_lab[TT];
    __shared__ unsigned long long s_bpkey[TT];
    __shared__ float s_btov[DMAX];
    __shared__ unsigned short s_btidx[DMAX];
    __shared__ float s_rf[4];
    __shared__ int   s_ri[4];

    if (tid < TT) {
        const float* tg = targets + ((size_t)b * TT + tid) * 5;
        float x1 = tg[0], y1 = tg[1], x2 = tg[2], y2 = tg[3];
        s_tr[tid][0] = x1; s_tr[tid][1] = y1; s_tr[tid][2] = x2; s_tr[tid][3] = y2;
        s_area[tid] = (x2 - x1) * (y2 - y1);
        s_lab[tid] = (int)tg[4];
        s_bpkey[tid] = 0ull;
    }
    __syncthreads();

    unsigned long long lkey[TT];
#pragma unroll
    for (int t = 0; t < TT; ++t) lkey[t] = 0ull;

    for (int d = tid; d < D; d += blockDim.x) {
        float4 db = ((const float4*)dbox)[d];
        float dx1 = db.x - db.z * 0.5f, dy1 = db.y - db.w * 0.5f;
        float dx2 = db.x + db.z * 0.5f, dy2 = db.y + db.w * 0.5f;
        float area_d = (dx2 - dx1) * (dy2 - dy1);
        float best = -1.0f; int bi = 0;
#pragma unroll
        for (int t = 0; t < TT; ++t) {
            float lx = fmaxf(s_tr[t][0], dx1);
            float ly = fmaxf(s_tr[t][1], dy1);
            float rx = fminf(s_tr[t][2], dx2);
            float ry = fminf(s_tr[t][3], dy2);
            float w = fmaxf(rx - lx, 0.0f), h = fmaxf(ry - ly, 0.0f);
            float inter = w * h;
            float iou = inter / (s_area[t] + area_d - inter);
            if (iou > best) { best = iou; bi = t; }   // strict >: first-max
            unsigned long long key =
                ((unsigned long long)__float_as_uint(iou) << 32) | (unsigned)(~(unsigned)d);
            if (key > lkey[t]) lkey[t] = key;         // max-value, min-index tie-break
        }
        s_btov[d] = best;
        s_btidx[d] = (unsigned short)bi;
    }
#pragma unroll
    for (int t = 0; t < TT; ++t) atomicMax(&s_bpkey[t], lkey[t]);
    __syncthreads();

    if (tid == 0) {
#pragma unroll
        for (int t = 0; t < TT; ++t) {
            unsigned d = ~(unsigned)(s_bpkey[t] & 0xFFFFFFFFu);
            if (d < (unsigned)D) {
                s_btov[d] = 2.0f;
                s_btidx[d] = (unsigned short)t;
            }
        }
    }
    __syncthreads();

    int local_pos = 0;
    float local_l1 = 0.0f;
    for (int d = tid; d < D; d += blockDim.x) {
        float ov = s_btov[d];
        int ti = s_btidx[d];
        int c = (ov < JT) ? 0 : (s_lab[ti] + 1);
        conf_t[(size_t)b * D + d] = c;
        if (c > 0) {
            ++local_pos;
            float4 db = ((const float4*)dbox)[d];
            float tx1 = s_tr[ti][0], ty1 = s_tr[ti][1], tx2 = s_tr[ti][2], ty2 = s_tr[ti][3];
            float mcx = (tx1 + tx2) * 0.5f, mcy = (ty1 + ty2) * 0.5f;
            float mw = tx2 - tx1, mh = ty2 - ty1;
            float gx = (mcx - db.x) / (0.1f * db.z);
            float gy = (mcy - db.y) / (0.1f * db.w);
            float gw = logf(mw / db.z) / 0.2f;
            float gh = logf(mh / db.w) / 0.2f;
            float4 lv = ((const float4*)loc)[(size_t)b * D + d];
            local_l1 += sl1(lv.x - gx) + sl1(lv.y - gy) + sl1(lv.z - gw) + sl1(lv.w - gh);
        }
    }

    for (int o = 32; o; o >>= 1) {
        local_l1 += __shfl_down(local_l1, o);
        local_pos += __shfl_down(local_pos, o);
    }
    int wv = tid >> 6;
    if ((tid & 63) == 0) { s_rf[wv] = local_l1; s_ri[wv] = local_pos; }
    __syncthreads();
    if (tid == 0) {
        float L = 0.0f; int P = 0;
        for (int w = 0; w < 4; ++w) { L += s_rf[w]; P += s_ri[w]; }
        loss_l_part[b] = L;
        num_pos[b] = P;
        posce[b] = 0.0f;
    }
}

// --- Kernel B: CE v7 — wave per 4-row group; 81 aligned float4 per group ---
// 4 rows * 324B = 1296B = 81 * 16B exactly -> every load is a full-width
// coalesced dwordx4 (1 KB per wave-instruction).
__global__ __launch_bounds__(256) void ce_kernel(
    const float* __restrict__ conf, const int* __restrict__ conf_t,
    int Rtot, int D,
    float* __restrict__ lossc, float* __restrict__ posce)
{
    const int lane = threadIdx.x & 63;
    const int waveId = threadIdx.x >> 6;
    const int gw = blockIdx.x * 4 + waveId;          // global wave id, 8732 total
    const float4* __restrict__ conf4 = (const float4*)conf;

    // loop-invariant per-lane row split for the first 64 float4s (floats 4L..4L+3)
    const int f0 = 4 * lane;
    const int rlo = f0 / 81;              // 0..3
    const int rhi = (f0 + 3) / 81;        // rlo or rlo+1
    const int sp = 81 * rhi - f0;         // floats in low row when straddling (1..3)

    for (int g = gw * 16, ge = g + 16; g < ge; ++g) {
        const size_t gbase = (size_t)g * 81;
        const float4 a = conf4[gbase + lane];
        float4 bq = make_float4(0.f, 0.f, 0.f, 0.f);
        if (lane < 17) bq = conf4[gbase + 64 + lane];   // float4 64..80

        float ex = __expf(a.x), ey = __expf(a.y), ez = __expf(a.z), ew = __expf(a.w);
        float sumAll = (ex + ey) + (ez + ew);
        float sumHi = 0.0f;
        if (rhi != rlo)
            sumHi = (sp == 1) ? (ey + ez + ew) : (sp == 2) ? (ez + ew) : ew;
        float sumLo = sumAll - sumHi;
        float s3 = 0.0f;
        if (lane < 17)
            s3 = (__expf(bq.x) + __expf(bq.y)) + (__expf(bq.z) + __expf(bq.w));

        float v0 = (rlo == 0) ? sumLo : 0.0f;
        float v1 = (rlo == 1) ? sumLo : ((rhi == 1) ? sumHi : 0.0f);
        float v2 = (rlo == 2) ? sumLo : ((rhi == 2) ? sumHi : 0.0f);
        float v3 = ((rlo == 3) ? sumLo : ((rhi == 3) ? sumHi : 0.0f)) + s3;

#pragma unroll
        for (int o = 32; o; o >>= 1) {
            v0 += __shfl_xor(v0, o);
            v1 += __shfl_xor(v1, o);
            v2 += __shfl_xor(v2, o);
            v3 += __shfl_xor(v3, o);
        }

        if (lane < 4) {
            float sr = (lane == 0) ? v0 : (lane == 1) ? v1 : (lane == 2) ? v2 : v3;
            const int row = g * 4 + lane;
            const int c = conf_t[row];
            const float xt = conf[(size_t)row * CC + c];   // L1 hit: row just streamed
            float cev = __logf(sr) - xt;
            lossc[row] = (c > 0) ? 0.0f : cev;
            if (c > 0) atomicAdd(&posce[row / D], cev);    // rare
        }
    }
}

// ---------------- Kernel C: HNM bit-bisection, 1 barrier/round ----------------
__global__ __launch_bounds__(256) void hnm_kernel(
    const float* __restrict__ lossc, const int* __restrict__ num_pos,
    const float* __restrict__ posce, int D,
    float* __restrict__ hnm)
{
    const int b = blockIdx.x;
    const int tid = threadIdx.x;
    __shared__ unsigned s_bits[DMAX];
    __shared__ int s_cnt[2][4];     // double-buffered by round parity
    __shared__ float s_sf[4];

    for (int d = tid; d < D; d += blockDim.x)
        s_bits[d] = __float_as_uint(lossc[(size_t)b * D + d]);
    const int k = min(num_pos[b] * 3, D);
    __syncthreads();

    unsigned T = 0;
    for (int bit = 30; bit >= 0; --bit) {   // finite non-negative floats: bit31=0
        const int ph = bit & 1;
        unsigned cand = T | (1u << bit);
        int cnt = 0;
        for (int d = tid; d < D; d += blockDim.x) cnt += (s_bits[d] >= cand) ? 1 : 0;
        for (int o = 32; o; o >>= 1) cnt += __shfl_down(cnt, o);
        if ((tid & 63) == 0) s_cnt[ph][tid >> 6] = cnt;
        __syncthreads();
        int tot = s_cnt[ph][0] + s_cnt[ph][1] + s_cnt[ph][2] + s_cnt[ph][3];
        if (tot >= k) T = cand;
        // next round writes the other parity slot: no second barrier needed
    }

    int cgt = 0; float sgt = 0.0f;
    for (int d = tid; d < D; d += blockDim.x) {
        unsigned v = s_bits[d];
        if (v > T) { ++cgt; sgt += __uint_as_float(v); }
    }
    for (int o = 32; o; o >>= 1) { cgt += __shfl_down(cgt, o); sgt += __shfl_down(sgt, o); }
    if ((tid & 63) == 0) { s_cnt[0][tid >> 6] = cgt; s_sf[tid >> 6] = sgt; }
    __syncthreads();
    if (tid == 0) {
        int C_gt = s_cnt[0][0] + s_cnt[0][1] + s_cnt[0][2] + s_cnt[0][3];
        float S_gt = s_sf[0] + s_sf[1] + s_sf[2] + s_sf[3];
        hnm[b] = posce[b] + S_gt + (float)(k - C_gt) * __uint_as_float(T);
    }
}

// ---------------- Kernel D: finalize ----------------
__global__ void finalize_kernel(
    const int* __restrict__ num_pos, const float* __restrict__ loss_l_part,
    const float* __restrict__ hnm, int B, float* __restrict__ out)
{
    int lane = threadIdx.x;
    int np = 0; float ll = 0.0f, lc = 0.0f;
    for (int b = lane; b < B; b += 64) {
        np += num_pos[b]; ll += loss_l_part[b]; lc += hnm[b];
    }
    for (int o = 32; o; o >>= 1) {
        np += __shfl_down(np, o); ll += __shfl_down(ll, o); lc += __shfl_down(lc, o);
    }
    if (lane == 0) {
        float N = (float)np;
        out[0] = ll / N;
        out[1] = lc / N;
    }
}

extern "C" void kernel_launch(void* const* d_in, const int* in_sizes, int n_in,
                              void* d_out, int out_size, void* d_ws, size_t ws_size,
                              hipStream_t stream) {
    const float* loc     = (const float*)d_in[0];
    const float* conf    = (const float*)d_in[1];
    const float* dbox    = (const float*)d_in[2];
    const float* targets = (const float*)d_in[3];

    const int D = in_sizes[2] / 4;               // 8732
    const int B = in_sizes[0] / (D * 4);         // 64
    const int Rtot = B * D;                      // 558848 = 8732 waves * 64 rows

    char* p = (char*)d_ws;
    int*   conf_t      = (int*)p;   p += (size_t)B * D * sizeof(int);
    float* lossc       = (float*)p; p += (size_t)B * D * sizeof(float);
    int*   num_pos     = (int*)p;   p += (size_t)B * sizeof(int);
    float* loss_l_part = (float*)p; p += (size_t)B * sizeof(float);
    float* posce       = (float*)p; p += (size_t)B * sizeof(float);
    float* hnm         = (float*)p; p += (size_t)B * sizeof(float);

    match_kernel<8><<<B, 256, 0, stream>>>(loc, dbox, targets, D,
                                           conf_t, num_pos, loss_l_part, posce);
    const int ceBlocks = 2183;                   // 8732 waves / 4 per block
    ce_kernel<<<ceBlocks, 256, 0, stream>>>(conf, conf_t, Rtot, D, lossc, posce);
    hnm_kernel<<<B, 256, 0, stream>>>(lossc, num_pos, posce, D, hnm);
    finalize_kernel<<<1, 64, 0, stream>>>(num_pos, loss_l_part, hnm, B, (float*)d_out);
}

// Round 8
// 204.396 us; speedup vs baseline: 1.0318x; 1.0318x over previous
//
#include <hip/hip_runtime.h>
#include <cstdint>
#include <cstddef>

#define DMAX 8732
#define JT 0.5f
#define CC 81

__device__ __forceinline__ float sl1(float d) {
    float ad = fabsf(d);
    return (ad < 1.0f) ? 0.5f * d * d : ad - 0.5f;
}

// ---------------- Kernel A: per-batch matching ----------------
template<int TT>
__global__ __launch_bounds__(256) void match_kernel(
    const float* __restrict__ loc, const float* __restrict__ dbox,
    const float* __restrict__ targets, int D,
    int* __restrict__ conf_t, int* __restrict__ num_pos,
    float* __restrict__ loss_l_part, float* __restrict__ posce)
{
    const int b = blockIdx.x;
    const int tid = threadIdx.x;

    __shared__ float s_tr[TT][4];
    __shared__ float s_area[TT];
    __shared__ int   s_lab[TT];
    __shared__ unsigned long long s_bpkey[TT];
    __shared__ float s_btov[DMAX];
    __shared__ unsigned short s_btidx[DMAX];
    __shared__ float s_rf[4];
    __shared__ int   s_ri[4];

    if (tid < TT) {
        const float* tg = targets + ((size_t)b * TT + tid) * 5;
        float x1 = tg[0], y1 = tg[1], x2 = tg[2], y2 = tg[3];
        s_tr[tid][0] = x1; s_tr[tid][1] = y1; s_tr[tid][2] = x2; s_tr[tid][3] = y2;
        s_area[tid] = (x2 - x1) * (y2 - y1);
        s_lab[tid] = (int)tg[4];
        s_bpkey[tid] = 0ull;
    }
    __syncthreads();

    unsigned long long lkey[TT];
#pragma unroll
    for (int t = 0; t < TT; ++t) lkey[t] = 0ull;

    for (int d = tid; d < D; d += blockDim.x) {
        float4 db = ((const float4*)dbox)[d];
        float dx1 = db.x - db.z * 0.5f, dy1 = db.y - db.w * 0.5f;
        float dx2 = db.x + db.z * 0.5f, dy2 = db.y + db.w * 0.5f;
        float area_d = (dx2 - dx1) * (dy2 - dy1);
        float best = -1.0f; int bi = 0;
#pragma unroll
        for (int t = 0; t < TT; ++t) {
            float lx = fmaxf(s_tr[t][0], dx1);
            float ly = fmaxf(s_tr[t][1], dy1);
            float rx = fminf(s_tr[t][2], dx2);
            float ry = fminf(s_tr[t][3], dy2);
            float w = fmaxf(rx - lx, 0.0f), h = fmaxf(ry - ly, 0.0f);
            float inter = w * h;
            float iou = inter / (s_area[t] + area_d - inter);
            if (iou > best) { best = iou; bi = t; }   // strict >: first-max
            unsigned long long key =
                ((unsigned long long)__float_as_uint(iou) << 32) | (unsigned)(~(unsigned)d);
            if (key > lkey[t]) lkey[t] = key;         // max-value, min-index tie-break
        }
        s_btov[d] = best;
        s_btidx[d] = (unsigned short)bi;
    }
#pragma unroll
    for (int t = 0; t < TT; ++t) atomicMax(&s_bpkey[t], lkey[t]);
    __syncthreads();

    if (tid == 0) {
#pragma unroll
        for (int t = 0; t < TT; ++t) {
            unsigned d = ~(unsigned)(s_bpkey[t] & 0xFFFFFFFFu);
            if (d < (unsigned)D) {
                s_btov[d] = 2.0f;
                s_btidx[d] = (unsigned short)t;
            }
        }
    }
    __syncthreads();

    int local_pos = 0;
    float local_l1 = 0.0f;
    for (int d = tid; d < D; d += blockDim.x) {
        float ov = s_btov[d];
        int ti = s_btidx[d];
        int c = (ov < JT) ? 0 : (s_lab[ti] + 1);
        conf_t[(size_t)b * D + d] = c;
        if (c > 0) {
            ++local_pos;
            float4 db = ((const float4*)dbox)[d];
            float tx1 = s_tr[ti][0], ty1 = s_tr[ti][1], tx2 = s_tr[ti][2], ty2 = s_tr[ti][3];
            float mcx = (tx1 + tx2) * 0.5f, mcy = (ty1 + ty2) * 0.5f;
            float mw = tx2 - tx1, mh = ty2 - ty1;
            float gx = (mcx - db.x) / (0.1f * db.z);
            float gy = (mcy - db.y) / (0.1f * db.w);
            float gw = logf(mw / db.z) / 0.2f;
            float gh = logf(mh / db.w) / 0.2f;
            float4 lv = ((const float4*)loc)[(size_t)b * D + d];
            local_l1 += sl1(lv.x - gx) + sl1(lv.y - gy) + sl1(lv.z - gw) + sl1(lv.w - gh);
        }
    }

    for (int o = 32; o; o >>= 1) {
        local_l1 += __shfl_down(local_l1, o);
        local_pos += __shfl_down(local_pos, o);
    }
    int wv = tid >> 6;
    if ((tid & 63) == 0) { s_rf[wv] = local_l1; s_ri[wv] = local_pos; }
    __syncthreads();
    if (tid == 0) {
        float L = 0.0f; int P = 0;
        for (int w = 0; w < 4; ++w) { L += s_rf[w]; P += s_ri[w]; }
        loss_l_part[b] = L;
        num_pos[b] = P;
        posce[b] = 0.0f;
    }
}

// ------- Kernel B: CE v5 (measured-best) — 16 lanes/row, coalesced stripes -------
__global__ __launch_bounds__(256) void ce_kernel(
    const float* __restrict__ conf, const int* __restrict__ conf_t,
    int Rtot, int D,
    float* __restrict__ lossc, float* __restrict__ posce)
{
    const int wave_in_blk = threadIdx.x >> 6;
    const int lane = threadIdx.x & 63;
    const int q = lane >> 4;        // quarter 0..3 -> row offset within group of 4
    const int l = lane & 15;        // lane within 16-lane row team

    const int row0 = blockIdx.x * 256 + wave_in_blk * 64;

#pragma unroll 4
    for (int i = 0; i < 16; ++i) {
        const int row = row0 + i * 4 + q;
        const float* __restrict__ x = conf + (size_t)row * CC;

        // 5 coalesced stripes cover indices 0..79 for every l (l+64 <= 79)
        float v0 = x[l];
        float v1 = x[l + 16];
        float v2 = x[l + 32];
        float v3 = x[l + 48];
        float v4 = x[l + 64];
        float v5 = (l == 0) ? x[80] : 0.0f;
        const int c = conf_t[row];

        float s = __expf(v0) + __expf(v1) + __expf(v2) + __expf(v3) + __expf(v4);
        if (l == 0) s += __expf(v5);

        float xt = 0.0f;
        xt += (l      == c) ? v0 : 0.0f;
        xt += (l + 16 == c) ? v1 : 0.0f;
        xt += (l + 32 == c) ? v2 : 0.0f;
        xt += (l + 48 == c) ? v3 : 0.0f;
        xt += (l + 64 == c) ? v4 : 0.0f;
        xt += (l == 0 && c == 80) ? v5 : 0.0f;

#pragma unroll
        for (int o = 8; o; o >>= 1) {
            s  += __shfl_xor(s, o);
            xt += __shfl_xor(xt, o);
        }

        if (l == 0) {
            float ce = __logf(s) - xt;
            lossc[row] = (c > 0) ? 0.0f : ce;
            if (c > 0) atomicAdd(&posce[row / D], ce);   // rare
        }
    }
}

// ---------------- Kernel C: HNM bit-bisection, 1 barrier/round ----------------
__global__ __launch_bounds__(256) void hnm_kernel(
    const float* __restrict__ lossc, const int* __restrict__ num_pos,
    const float* __restrict__ posce, int D,
    float* __restrict__ hnm)
{
    const int b = blockIdx.x;
    const int tid = threadIdx.x;
    __shared__ unsigned s_bits[DMAX];
    __shared__ int s_cnt[2][4];     // double-buffered by round parity
    __shared__ float s_sf[4];

    for (int d = tid; d < D; d += blockDim.x)
        s_bits[d] = __float_as_uint(lossc[(size_t)b * D + d]);
    const int k = min(num_pos[b] * 3, D);
    __syncthreads();

    unsigned T = 0;
    for (int bit = 30; bit >= 0; --bit) {   // finite non-negative floats: bit31=0
        const int ph = bit & 1;
        unsigned cand = T | (1u << bit);
        int cnt = 0;
        for (int d = tid; d < D; d += blockDim.x) cnt += (s_bits[d] >= cand) ? 1 : 0;
        for (int o = 32; o; o >>= 1) cnt += __shfl_down(cnt, o);
        if ((tid & 63) == 0) s_cnt[ph][tid >> 6] = cnt;
        __syncthreads();
        int tot = s_cnt[ph][0] + s_cnt[ph][1] + s_cnt[ph][2] + s_cnt[ph][3];
        if (tot >= k) T = cand;
        // next round writes the other parity slot: no second barrier needed
    }

    int cgt = 0; float sgt = 0.0f;
    for (int d = tid; d < D; d += blockDim.x) {
        unsigned v = s_bits[d];
        if (v > T) { ++cgt; sgt += __uint_as_float(v); }
    }
    for (int o = 32; o; o >>= 1) { cgt += __shfl_down(cgt, o); sgt += __shfl_down(sgt, o); }
    if ((tid & 63) == 0) { s_cnt[0][tid >> 6] = cgt; s_sf[tid >> 6] = sgt; }
    __syncthreads();
    if (tid == 0) {
        int C_gt = s_cnt[0][0] + s_cnt[0][1] + s_cnt[0][2] + s_cnt[0][3];
        float S_gt = s_sf[0] + s_sf[1] + s_sf[2] + s_sf[3];
        hnm[b] = posce[b] + S_gt + (float)(k - C_gt) * __uint_as_float(T);
    }
}

// ---------------- Kernel D: finalize ----------------
__global__ void finalize_kernel(
    const int* __restrict__ num_pos, const float* __restrict__ loss_l_part,
    const float* __restrict__ hnm, int B, float* __restrict__ out)
{
    int lane = threadIdx.x;
    int np = 0; float ll = 0.0f, lc = 0.0f;
    for (int b = lane; b < B; b += 64) {
        np += num_pos[b]; ll += loss_l_part[b]; lc += hnm[b];
    }
    for (int o = 32; o; o >>= 1) {
        np += __shfl_down(np, o); ll += __shfl_down(ll, o); lc += __shfl_down(lc, o);
    }
    if (lane == 0) {
        float N = (float)np;
        out[0] = ll / N;
        out[1] = lc / N;
    }
}

extern "C" void kernel_launch(void* const* d_in, const int* in_sizes, int n_in,
                              void* d_out, int out_size, void* d_ws, size_t ws_size,
                              hipStream_t stream) {
    const float* loc     = (const float*)d_in[0];
    const float* conf    = (const float*)d_in[1];
    const float* dbox    = (const float*)d_in[2];
    const float* targets = (const float*)d_in[3];

    const int D = in_sizes[2] / 4;               // 8732
    const int B = in_sizes[0] / (D * 4);         // 64
    const int Rtot = B * D;                      // 558848 = 2183 * 256

    char* p = (char*)d_ws;
    int*   conf_t      = (int*)p;   p += (size_t)B * D * sizeof(int);
    float* lossc       = (float*)p; p += (size_t)B * D * sizeof(float);
    int*   num_pos     = (int*)p;   p += (size_t)B * sizeof(int);
    float* loss_l_part = (float*)p; p += (size_t)B * sizeof(float);
    float* posce       = (float*)p; p += (size_t)B * sizeof(float);
    float* hnm         = (float*)p; p += (size_t)B * sizeof(float);

    match_kernel<8><<<B, 256, 0, stream>>>(loc, dbox, targets, D,
                                           conf_t, num_pos, loss_l_part, posce);
    const int ceBlocks = Rtot / 256;             // 2183 exactly
    ce_kernel<<<ceBlocks, 256, 0, stream>>>(conf, conf_t, Rtot, D, lossc, posce);
    hnm_kernel<<<B, 256, 0, stream>>>(lossc, num_pos, posce, D, hnm);
    finalize_kernel<<<1, 64, 0, stream>>>(num_pos, loss_l_part, hnm, B, (float*)d_out);
}